// Round 16
// baseline (103.509 us; speedup 1.0000x reference)
//
#include <hip/hip_runtime.h>
#include <hip/hip_bf16.h>

typedef _Float16 f16;
typedef f16 f16x8 __attribute__((ext_vector_type(8)));
typedef f16 f16x4 __attribute__((ext_vector_type(4)));
typedef __fp16 h16x2 __attribute__((ext_vector_type(2)));
typedef float f32x4 __attribute__((ext_vector_type(4)));

#define MFMA_F16(a, b, c) __builtin_amdgcn_mfma_f32_16x16x32_f16((a), (b), (c), 0, 0, 0)
#define LOG2E 1.44269504f
#define EXP2(x) __builtin_amdgcn_exp2f(x)

// ---------------------------------------------------------------------------
// async global->LDS 16B copy
// ---------------------------------------------------------------------------
__device__ __forceinline__ void ld_lds16(const void* g, void* l) {
  __builtin_amdgcn_global_load_lds((const __attribute__((address_space(1))) void*)g,
                                   (__attribute__((address_space(3))) void*)l, 16, 0, 0);
}

// ---------------------------------------------------------------------------
// fused: cast fp32 -> fp16 (wq scaled by log2e) + bias table build
// ---------------------------------------------------------------------------
__global__ __launch_bounds__(256) void cast_and_bias(
    const float* __restrict__ hs, const float* __restrict__ wq,
    const float* __restrict__ wk, const float* __restrict__ wv,
    const float* __restrict__ wo, const float* __restrict__ rb,
    f16* __restrict__ hb, f16* __restrict__ wqb, f16* __restrict__ wkb,
    f16* __restrict__ wvb, f16* __restrict__ wob, float* __restrict__ btab) {
  if (blockIdx.x < 6144) {
    int idx = blockIdx.x * 256 + threadIdx.x;  // 1,572,864 float4 chunks
    const float* src;
    f16* dst;
    int j;
    float scale = 1.0f;
    if (idx < 524288) {  // hidden: 2M floats / 4
      src = hs; dst = hb; j = idx;
    } else {
      int t = idx - 524288;
      int w = t >> 18;      // 262144 float4 per weight
      j = t & 262143;
      src = (w == 0) ? wq : (w == 1) ? wk : (w == 2) ? wv : wo;
      dst = (w == 0) ? wqb : (w == 1) ? wkb : (w == 2) ? wvb : wob;
      if (w == 0) scale = LOG2E;
    }
    float4 v = ((const float4*)src)[j];
    f16x4 o;
    o[0] = (f16)(v.x * scale); o[1] = (f16)(v.y * scale);
    o[2] = (f16)(v.z * scale); o[3] = (f16)(v.w * scale);
    ((f16x4*)dst)[j] = o;
  } else {
    int idx = (blockIdx.x - 6144) * 256 + threadIdx.x;  // 65536 = 16h * 4096
    int h = idx >> 12;
    int t = idx & 4095;
    int rel = t - 2047;
    int bucket = (rel > 0) ? 16 : 0;
    int a = (rel < 0) ? -rel : rel;
    int lg;
    if (a < 8) {
      lg = a;
    } else {
      int cnt = (a >= 12) + (a >= 16) + (a >= 23) + (a >= 32) + (a >= 46) +
                (a >= 64) + (a >= 91);
      lg = 8 + cnt;  // max 15
    }
    bucket += lg;
    btab[idx] = rb[bucket * 16 + h] * LOG2E;  // rel_bias[32][16]
  }
}

// ---------------------------------------------------------------------------
// GEMM mainloop, templated on MR: MR=4 -> 64x128 tile, MR=2 -> 32x128 tile.
// Double-buffered: stage(k+64) before compute(k), one barrier/iter.
// ---------------------------------------------------------------------------
template <int MR>
__device__ __forceinline__ void gemm_mainloop(const f16* __restrict__ A,
                                              const f16* __restrict__ B,
                                              int brow, int bcol,
                                              f16 (*lA)[MR * 16 * 64],
                                              f16 (*lB)[128 * 64],
                                              f32x4 acc[MR][2]) {
  const int tid = threadIdx.x;
  const int lane = tid & 63;
  const int wn = tid >> 6;
  const int lo = lane & 15;
  const int hi = lane >> 4;
  const int sw = lo & 7;
  const int sr = tid >> 3;                       // 0..31
  const int se = (((tid & 7) ^ (sr & 7)) << 3);  // swizzled col elem offset
  const f16* gA = A + (size_t)(brow + sr) * 1024 + se;
  const f16* gB = B + (size_t)(bcol + sr) * 1024 + se;

#define GSTAGE(bi, k0_)                                                        \
  do {                                                                         \
    ld_lds16(gA + (k0_), lA[bi] + tid * 8);                                    \
    if constexpr (MR == 4)                                                     \
      ld_lds16(gA + (k0_) + 32 * 1024, lA[bi] + tid * 8 + 2048);               \
    ld_lds16(gB + (k0_),             lB[bi] + tid * 8);                        \
    ld_lds16(gB + (k0_) + 32 * 1024, lB[bi] + tid * 8 + 2048);                 \
    ld_lds16(gB + (k0_) + 64 * 1024, lB[bi] + tid * 8 + 4096);                 \
    ld_lds16(gB + (k0_) + 96 * 1024, lB[bi] + tid * 8 + 6144);                 \
  } while (0)

  GSTAGE(0, 0);
  __syncthreads();
  for (int k0 = 0; k0 < 1024; k0 += 64) {
    const int bi = (k0 >> 6) & 1;
    if (k0 < 960) GSTAGE(bi ^ 1, k0 + 64);
    f16x8 af[MR][2], bf[2][2];
#pragma unroll
    for (int m = 0; m < MR; ++m)
#pragma unroll
      for (int ks = 0; ks < 2; ++ks)
        af[m][ks] = *(const f16x8*)(lA[bi] + (m * 16 + lo) * 64 +
                                    (((ks << 2) | hi) ^ sw) * 8);
#pragma unroll
    for (int j = 0; j < 2; ++j)
#pragma unroll
      for (int ks = 0; ks < 2; ++ks)
        bf[j][ks] = *(const f16x8*)(lB[bi] + (wn * 32 + j * 16 + lo) * 64 +
                                    (((ks << 2) | hi) ^ sw) * 8);
    __builtin_amdgcn_s_setprio(1);
#pragma unroll
    for (int m = 0; m < MR; ++m)
#pragma unroll
      for (int j = 0; j < 2; ++j)
#pragma unroll
        for (int ks = 0; ks < 2; ++ks)
          acc[m][j] = MFMA_F16(af[m][ks], bf[j][ks], acc[m][j]);
    __builtin_amdgcn_s_setprio(0);
    __syncthreads();  // stage(bi^1) retired + everyone done reading bi
  }
#undef GSTAGE
}

// QKV projections fused over blockIdx.z (0=Q, 1=K, 2=V-transposed+pi-permuted)
__global__ __launch_bounds__(256) void gemm_qkv(
    const f16* __restrict__ A, const f16* __restrict__ Wq,
    const f16* __restrict__ Wk, const f16* __restrict__ Wv,
    f16* __restrict__ Qo, f16* __restrict__ Ko, f16* __restrict__ VTo) {
  __shared__ __align__(16) f16 lA[2][64 * 64];
  __shared__ __align__(16) f16 lB[2][128 * 64];
  const int z = blockIdx.z;
  const f16* B = (z == 0) ? Wq : (z == 1) ? Wk : Wv;
  const int brow = blockIdx.x * 64, bcol = blockIdx.y * 128;
  f32x4 acc[4][2];
#pragma unroll
  for (int m = 0; m < 4; ++m)
#pragma unroll
    for (int j = 0; j < 2; ++j) acc[m][j] = f32x4{0.f, 0.f, 0.f, 0.f};
  gemm_mainloop<4>(A, B, brow, bcol, lA, lB, acc);
  const int lane = threadIdx.x & 63, wn = threadIdx.x >> 6;
  const int lo = lane & 15, hi = lane >> 4;
  if (z < 2) {
    f16* C = z ? Ko : Qo;
#pragma unroll
    for (int m = 0; m < 4; ++m)
#pragma unroll
      for (int j = 0; j < 2; ++j) {
        int col = bcol + wn * 32 + j * 16 + lo;
        int row0 = brow + m * 16 + hi * 4;
#pragma unroll
        for (int r = 0; r < 4; ++r)
          C[(size_t)(row0 + r) * 1024 + col] = (f16)acc[m][j][r];
      }
  } else {
    // V transposed: VT[n][s'], pi-permuted within each 64-kv block so a PV
    // fragment is one contiguous b128 in LDS.
#pragma unroll
    for (int m = 0; m < 4; ++m)
#pragma unroll
      for (int j = 0; j < 2; ++j) {
        int col = bcol + wn * 32 + j * 16 + lo;   // n
        int g = m * 4 + hi;
        int w = g & 7;
        int gp = (g & 8) | ((w < 4) ? (2 * w) : (2 * (w - 4) + 1));
        int sp = brow + gp * 4;                   // permuted s
        f16x4 v4;
#pragma unroll
        for (int r = 0; r < 4; ++r) v4[r] = (f16)acc[m][j][r];
        *(f16x4*)(VTo + (size_t)col * 2048 + sp) = v4;
      }
  }
}

// output projection: AO[2048,1024] * Wo[1024,1024]^T -> fp32 d_out
__global__ __launch_bounds__(256) void gemm_out(const f16* __restrict__ A,
                                                const f16* __restrict__ W,
                                                float* __restrict__ C) {
  __shared__ __align__(16) f16 lA[2][32 * 64];
  __shared__ __align__(16) f16 lB[2][128 * 64];
  const int brow = blockIdx.x * 32, bcol = blockIdx.y * 128;
  f32x4 acc[2][2];
#pragma unroll
  for (int m = 0; m < 2; ++m)
#pragma unroll
    for (int j = 0; j < 2; ++j) acc[m][j] = f32x4{0.f, 0.f, 0.f, 0.f};
  gemm_mainloop<2>(A, W, brow, bcol, lA, lB, acc);
  const int lane = threadIdx.x & 63, wn = threadIdx.x >> 6;
  const int lo = lane & 15, hi = lane >> 4;
#pragma unroll
  for (int m = 0; m < 2; ++m)
#pragma unroll
    for (int j = 0; j < 2; ++j) {
      int col = bcol + wn * 32 + j * 16 + lo;
      int row0 = brow + m * 16 + hi * 4;
#pragma unroll
      for (int r = 0; r < 4; ++r)
        C[(size_t)(row0 + r) * 1024 + col] = acc[m][j][r];
    }
}

// ---------------------------------------------------------------------------
// Flash attention v14 = r9 structure x v13 micro-opts:
// 32q/wave (K/V frags shared across 2 q-halves -> LDS reads halved), kv
// z-split (2x1024) keeping 512 blocks = 2 waves/SIMD, pi-permuted V (one
// b128/frag), shfl-free softmax (lane-local l, ballot-gated max), exp2
// domain, bias-in-C-init with far-tile scalars, cvt_pkrtz P pack.
// Partials (normalized O + m,l) merged exactly by merge_halves.
// ---------------------------------------------------------------------------
__global__ __launch_bounds__(256) void attn_kernel(
    const f16* __restrict__ Q, const f16* __restrict__ K,
    const f16* __restrict__ VT, const float* __restrict__ btab,
    f16* __restrict__ Oh, float2* __restrict__ Ml) {
  __shared__ __align__(16) f16 lK[2][4096];
  __shared__ __align__(16) f16 lV[2][4096];

  const int h = blockIdx.y;
  const int q0 = blockIdx.x * 128;
  const int z = blockIdx.z;
  const int kvbase = z * 1024;
  const int tid = threadIdx.x;
  const int wave = tid >> 6, lane = tid & 63;
  const int lo = lane & 15, hi = lane >> 4;
  const int sw = lo & 7;
  const int qlo = q0 + wave * 32;
  const int myq0 = qlo + lo;
  const int myq1 = qlo + 16 + lo;

  const f16* Kh = K + h * 64;
  const f16* VTh = VT + (size_t)h * 64 * 2048;
  const float* bt0 = btab + h * 4096 + 2047 - myq0;
  const float* bt1 = btab + h * 4096 + 2047 - myq1;

  // Q fragments [qh][kk]
  f16x8 qf[2][2];
#pragma unroll
  for (int kk = 0; kk < 2; ++kk) {
    qf[0][kk] = *(const f16x8*)(Q + (size_t)myq0 * 1024 + h * 64 + kk * 32 + hi * 8);
    qf[1][kk] = *(const f16x8*)(Q + (size_t)myq1 * 1024 + h * 64 + kk * 32 + hi * 8);
  }
  // far-tile scalar biases (saturated buckets), log2e-scaled
  const float bp = btab[h * 4096 + 4094];  // rel >= +91 (bucket 31)
  const float bn = btab[h * 4096 + 0];     // rel <= -91 (bucket 15)

  // staging chunk indices (2 chunks each for K and V per thread)
  const int sc0 = wave * 64 + lane;
  const int sc1 = 256 + sc0;
  const int r0 = sc0 >> 3, e0 = (sc0 & 7) ^ (r0 & 7);
  const int r1 = sc1 >> 3, e1 = (sc1 & 7) ^ (r1 & 7);

#define STAGE(bufi, kv)                                                        \
  do {                                                                         \
    ld_lds16(Kh + (size_t)((kv) + r0) * 1024 + e0 * 8, &lK[bufi][sc0 * 8]);    \
    ld_lds16(Kh + (size_t)((kv) + r1) * 1024 + e1 * 8, &lK[bufi][sc1 * 8]);    \
    ld_lds16(VTh + (size_t)r0 * 2048 + (kv) + e0 * 8, &lV[bufi][sc0 * 8]);     \
    ld_lds16(VTh + (size_t)r1 * 2048 + (kv) + e1 * 8, &lV[bufi][sc1 * 8]);     \
  } while (0)

  float m_run[2] = {-1e30f, -1e30f};
  float l_run[2] = {0.f, 0.f};  // LANE-LOCAL partials
  f32x4 oacc[4][2];
#pragma unroll
  for (int d = 0; d < 4; ++d)
#pragma unroll
    for (int qh = 0; qh < 2; ++qh) oacc[d][qh] = f32x4{0.f, 0.f, 0.f, 0.f};

  STAGE(0, kvbase);
  __syncthreads();

  for (int t = 0; t < 16; ++t) {
    const int kv0 = kvbase + t * 64;
    const int b = t & 1;
    if (t < 15) STAGE(b ^ 1, kv0 + 64);

    const f16* lKb = lK[b];
    const f16* lVb = lV[b];

    // ---- K frags (shared across both q-halves) ----
    f16x8 kf[4][2];
#pragma unroll
    for (int m = 0; m < 4; ++m)
#pragma unroll
      for (int kk = 0; kk < 2; ++kk)
        kf[m][kk] = *(const f16x8*)&lKb[(m * 16 + lo) * 64 +
                                        (((kk << 2) | hi) ^ sw) * 8];
    // ---- V frags: ONE b128 each (pi-permuted layout), shared across qh ----
    f16x8 vf[4][2];
#pragma unroll
    for (int d = 0; d < 4; ++d)
#pragma unroll
      for (int kk = 0; kk < 2; ++kk)
        vf[d][kk] = *(const f16x8*)&lVb[(d * 16 + lo) * 64 +
                                        ((kk * 4 + hi) ^ sw) * 8];

    // ---- bias (far tiles: wave-uniform scalar) ----
    const int rmin = kv0 - (qlo + 31);
    const int rmax = kv0 + 63 - qlo;
    float bias[2][16];
    if (rmin >= 91 || rmax <= -91) {
      const float bf_ = (rmin >= 91) ? bp : bn;
#pragma unroll
      for (int qh = 0; qh < 2; ++qh)
#pragma unroll
        for (int i = 0; i < 16; ++i) bias[qh][i] = bf_;
    } else {
#pragma unroll
      for (int i = 0; i < 16; ++i) {
        const int kvi = kv0 + (i >> 2) * 16 + hi * 4 + (i & 3);
        bias[0][i] = bt0[kvi];
        bias[1][i] = bt1[kvi];
      }
    }

    // ---- QK^T with bias in C-init ----
    f32x4 sacc[4][2];
    __builtin_amdgcn_s_setprio(1);
#pragma unroll
    for (int m = 0; m < 4; ++m)
#pragma unroll
      for (int qh = 0; qh < 2; ++qh) {
        sacc[m][qh] = f32x4{bias[qh][m * 4 + 0], bias[qh][m * 4 + 1],
                            bias[qh][m * 4 + 2], bias[qh][m * 4 + 3]};
#pragma unroll
        for (int kk = 0; kk < 2; ++kk)
          sacc[m][qh] = MFMA_F16(kf[m][kk], qf[qh][kk], sacc[m][qh]);
      }
    __builtin_amdgcn_s_setprio(0);

    // ---- softmax (exp2 domain, shfl-free common path) + PV per q-half ----
    f16x8 pf[2][2];
#pragma unroll
    for (int qh = 0; qh < 2; ++qh) {
      float p[16];
#pragma unroll
      for (int i = 0; i < 16; ++i) p[i] = sacc[i >> 2][qh][i & 3];
      float x8[8];
#pragma unroll
      for (int i = 0; i < 8; ++i) x8[i] = fmaxf(p[i], p[i + 8]);
      float x4[4];
#pragma unroll
      for (int i = 0; i < 4; ++i) x4[i] = fmaxf(x8[i], x8[i + 4]);
      float mxl = fmaxf(fmaxf(x4[0], x4[1]), fmaxf(x4[2], x4[3]));
      if (!__all(mxl <= m_run[qh] + 11.5416f)) {  // rare: real max update
        float mx = fmaxf(mxl, __shfl_xor(mxl, 16, 64));
        mx = fmaxf(mx, __shfl_xor(mx, 32, 64));
        float mn = fmaxf(m_run[qh], mx);
        float sc = EXP2(m_run[qh] - mn);
        l_run[qh] *= sc;
#pragma unroll
        for (int d = 0; d < 4; ++d) oacc[d][qh] *= sc;
        m_run[qh] = mn;
      }
#pragma unroll
      for (int i = 0; i < 16; ++i) p[i] = EXP2(p[i] - m_run[qh]);
      float s8[8];
#pragma unroll
      for (int i = 0; i < 8; ++i) s8[i] = p[i] + p[i + 8];
      float s4[4];
#pragma unroll
      for (int i = 0; i < 4; ++i) s4[i] = s8[i] + s8[i + 4];
      l_run[qh] += (s4[0] + s4[1]) + (s4[2] + s4[3]);  // lane-local
      union {
        h16x2 h2[4];
        f16x8 v8;
      } u0, u1;
#pragma unroll
      for (int j = 0; j < 4; ++j) {
        u0.h2[j] = __builtin_amdgcn_cvt_pkrtz(p[2 * j], p[2 * j + 1]);
        u1.h2[j] = __builtin_amdgcn_cvt_pkrtz(p[8 + 2 * j], p[9 + 2 * j]);
      }
      pf[qh][0] = u0.v8;
      pf[qh][1] = u1.v8;
    }

    __builtin_amdgcn_s_setprio(1);
#pragma unroll
    for (int d = 0; d < 4; ++d)
#pragma unroll
      for (int qh = 0; qh < 2; ++qh)
#pragma unroll
        for (int kk = 0; kk < 2; ++kk)
          oacc[d][qh] = MFMA_F16(vf[d][kk], pf[qh][kk], oacc[d][qh]);
    __builtin_amdgcn_s_setprio(0);

    __syncthreads();
  }
#undef STAGE

  // ---- epilogue: deferred l reduce, normalized partial -> Oh[z], Ml ----
  f16* OhZ = Oh + (size_t)z * 2048 * 1024;
#pragma unroll
  for (int qh = 0; qh < 2; ++qh) {
    float l = l_run[qh];
    l += __shfl_xor(l, 16, 64);
    l += __shfl_xor(l, 32, 64);
    const int myq = qh ? myq1 : myq0;
    float inv = 1.f / l;
#pragma unroll
    for (int d = 0; d < 4; ++d) {
      f16x4 ov;
#pragma unroll
      for (int r = 0; r < 4; ++r) ov[r] = (f16)(oacc[d][qh][r] * inv);
      *(f16x4*)(OhZ + (size_t)myq * 1024 + h * 64 + d * 16 + hi * 4) = ov;
    }
    if (hi == 0) Ml[(z * 16 + h) * 2048 + myq] = float2{m_run[qh], l};
  }
}

// ---------------------------------------------------------------------------
// exact merge of the two KV-half partials: AO = w0*Oh0 + w1*Oh1 (exp2 domain)
// ---------------------------------------------------------------------------
__global__ __launch_bounds__(256) void merge_halves(
    const f16* __restrict__ Oh, const float2* __restrict__ Ml,
    f16* __restrict__ AO) {
  int idx = blockIdx.x * 256 + threadIdx.x;  // 262144 f16x8 chunks
  int q = idx >> 7;                          // 128 chunks per q-row
  int h = (idx & 127) >> 3;                  // 8 chunks per head
  float2 ml0 = Ml[h * 2048 + q];
  float2 ml1 = Ml[(16 + h) * 2048 + q];
  float M = fmaxf(ml0.x, ml1.x);
  float w0 = ml0.y * EXP2(ml0.x - M);
  float w1 = ml1.y * EXP2(ml1.x - M);
  float inv = 1.f / (w0 + w1);
  w0 *= inv;
  w1 *= inv;
  f16x8 a = ((const f16x8*)Oh)[idx];
  f16x8 b = ((const f16x8*)(Oh + (size_t)2048 * 1024))[idx];
  f16x8 o;
#pragma unroll
  for (int r = 0; r < 8; ++r)
    o[r] = (f16)(w0 * (float)a[r] + w1 * (float)b[r]);
  ((f16x8*)AO)[idx] = o;
}

// ---------------------------------------------------------------------------
extern "C" void kernel_launch(void* const* d_in, const int* in_sizes, int n_in,
                              void* d_out, int out_size, void* d_ws, size_t ws_size,
                              hipStream_t stream) {
  const float* hs = (const float*)d_in[0];
  const float* wq = (const float*)d_in[1];
  const float* wk = (const float*)d_in[2];
  const float* wv = (const float*)d_in[3];
  const float* wo = (const float*)d_in[4];
  const float* rb = (const float*)d_in[5];

  char* w = (char*)d_ws;
  f16* hb  = (f16*)w; w += (size_t)2048 * 1024 * 2;
  f16* wqb = (f16*)w; w += (size_t)1024 * 1024 * 2;
  f16* wkb = (f16*)w; w += (size_t)1024 * 1024 * 2;
  f16* wvb = (f16*)w; w += (size_t)1024 * 1024 * 2;
  f16* wob = (f16*)w; w += (size_t)1024 * 1024 * 2;
  f16* Qb  = (f16*)w; w += (size_t)2048 * 1024 * 2;
  f16* Kb  = (f16*)w; w += (size_t)2048 * 1024 * 2;
  f16* VTb = (f16*)w; w += (size_t)2048 * 1024 * 2;
  f16* AOb = (f16*)w; w += (size_t)2048 * 1024 * 2;
  float* btab = (float*)w; w += (size_t)16 * 4096 * 4;

  // partial buffers reuse hb/wqb/wkb (8 MB, dead after gemm_qkv) and wvb:
  f16* Oh = hb;                 // [2][2048][1024] f16 = 8 MB
  float2* Ml = (float2*)wvb;    // [2][16][2048] float2 = 512 KB

  cast_and_bias<<<6400, 256, 0, stream>>>(hs, wq, wk, wv, wo, rb,
                                          hb, wqb, wkb, wvb, wob, btab);
  gemm_qkv<<<dim3(32, 8, 3), 256, 0, stream>>>(hb, wqb, wkb, wvb, Qb, Kb, VTb);
  attn_kernel<<<dim3(16, 16, 2), 256, 0, stream>>>(Qb, Kb, VTb, btab, Oh, Ml);
  merge_halves<<<1024, 256, 0, stream>>>(Oh, Ml, AOb);
  gemm_out<<<dim3(64, 8), 256, 0, stream>>>(AOb, wob, (float*)d_out);
}

// Round 17
// 78.524 us; speedup vs baseline: 1.3182x; 1.3182x over previous
//
#include <hip/hip_runtime.h>
#include <hip/hip_bf16.h>

typedef _Float16 f16;
typedef f16 f16x8 __attribute__((ext_vector_type(8)));
typedef f16 f16x4 __attribute__((ext_vector_type(4)));
typedef __fp16 h16x2 __attribute__((ext_vector_type(2)));
typedef float f32x4 __attribute__((ext_vector_type(4)));

#define MFMA_F16(a, b, c) __builtin_amdgcn_mfma_f32_16x16x32_f16((a), (b), (c), 0, 0, 0)
#define LOG2E 1.44269504f
#define EXP2(x) __builtin_amdgcn_exp2f(x)

// ---------------------------------------------------------------------------
// async global->LDS 16B copy
// ---------------------------------------------------------------------------
__device__ __forceinline__ void ld_lds16(const void* g, void* l) {
  __builtin_amdgcn_global_load_lds((const __attribute__((address_space(1))) void*)g,
                                   (__attribute__((address_space(3))) void*)l, 16, 0, 0);
}

// ---------------------------------------------------------------------------
// fused: cast fp32 -> fp16 (wq scaled by log2e) + bias table build
// blocks [0,6144): cast;  blocks [6144,6400): bias
// ---------------------------------------------------------------------------
__global__ __launch_bounds__(256) void cast_and_bias(
    const float* __restrict__ hs, const float* __restrict__ wq,
    const float* __restrict__ wk, const float* __restrict__ wv,
    const float* __restrict__ wo, const float* __restrict__ rb,
    f16* __restrict__ hb, f16* __restrict__ wqb, f16* __restrict__ wkb,
    f16* __restrict__ wvb, f16* __restrict__ wob, float* __restrict__ btab) {
  if (blockIdx.x < 6144) {
    int idx = blockIdx.x * 256 + threadIdx.x;  // 1,572,864 float4 chunks
    const float* src;
    f16* dst;
    int j;
    float scale = 1.0f;
    if (idx < 524288) {  // hidden: 2M floats / 4
      src = hs; dst = hb; j = idx;
    } else {
      int t = idx - 524288;
      int w = t >> 18;      // 262144 float4 per weight
      j = t & 262143;
      src = (w == 0) ? wq : (w == 1) ? wk : (w == 2) ? wv : wo;
      dst = (w == 0) ? wqb : (w == 1) ? wkb : (w == 2) ? wvb : wob;
      if (w == 0) scale = LOG2E;
    }
    float4 v = ((const float4*)src)[j];
    f16x4 o;
    o[0] = (f16)(v.x * scale); o[1] = (f16)(v.y * scale);
    o[2] = (f16)(v.z * scale); o[3] = (f16)(v.w * scale);
    ((f16x4*)dst)[j] = o;
  } else {
    int idx = (blockIdx.x - 6144) * 256 + threadIdx.x;  // 65536 = 16h * 4096
    int h = idx >> 12;
    int t = idx & 4095;
    int rel = t - 2047;
    int bucket = (rel > 0) ? 16 : 0;
    int a = (rel < 0) ? -rel : rel;
    int lg;
    if (a < 8) {
      lg = a;
    } else {
      int cnt = (a >= 12) + (a >= 16) + (a >= 23) + (a >= 32) + (a >= 46) +
                (a >= 64) + (a >= 91);
      lg = 8 + cnt;  // max 15
    }
    bucket += lg;
    btab[idx] = rb[bucket * 16 + h] * LOG2E;  // rel_bias[32][16]
  }
}

// ---------------------------------------------------------------------------
// GEMM mainloop, templated on MR: MR=4 -> 64x128 tile, MR=2 -> 32x128 tile.
// Double-buffered: stage(k+64) before compute(k), one barrier/iter.
// ---------------------------------------------------------------------------
template <int MR>
__device__ __forceinline__ void gemm_mainloop(const f16* __restrict__ A,
                                              const f16* __restrict__ B,
                                              int brow, int bcol,
                                              f16 (*lA)[MR * 16 * 64],
                                              f16 (*lB)[128 * 64],
                                              f32x4 acc[MR][2]) {
  const int tid = threadIdx.x;
  const int lane = tid & 63;
  const int wn = tid >> 6;
  const int lo = lane & 15;
  const int hi = lane >> 4;
  const int sw = lo & 7;
  const int sr = tid >> 3;                       // 0..31
  const int se = (((tid & 7) ^ (sr & 7)) << 3);  // swizzled col elem offset
  const f16* gA = A + (size_t)(brow + sr) * 1024 + se;
  const f16* gB = B + (size_t)(bcol + sr) * 1024 + se;

#define GSTAGE(bi, k0_)                                                        \
  do {                                                                         \
    ld_lds16(gA + (k0_), lA[bi] + tid * 8);                                    \
    if constexpr (MR == 4)                                                     \
      ld_lds16(gA + (k0_) + 32 * 1024, lA[bi] + tid * 8 + 2048);               \
    ld_lds16(gB + (k0_),             lB[bi] + tid * 8);                        \
    ld_lds16(gB + (k0_) + 32 * 1024, lB[bi] + tid * 8 + 2048);                 \
    ld_lds16(gB + (k0_) + 64 * 1024, lB[bi] + tid * 8 + 4096);                 \
    ld_lds16(gB + (k0_) + 96 * 1024, lB[bi] + tid * 8 + 6144);                 \
  } while (0)

  GSTAGE(0, 0);
  __syncthreads();
  for (int k0 = 0; k0 < 1024; k0 += 64) {
    const int bi = (k0 >> 6) & 1;
    if (k0 < 960) GSTAGE(bi ^ 1, k0 + 64);
    f16x8 af[MR][2], bf[2][2];
#pragma unroll
    for (int m = 0; m < MR; ++m)
#pragma unroll
      for (int ks = 0; ks < 2; ++ks)
        af[m][ks] = *(const f16x8*)(lA[bi] + (m * 16 + lo) * 64 +
                                    (((ks << 2) | hi) ^ sw) * 8);
#pragma unroll
    for (int j = 0; j < 2; ++j)
#pragma unroll
      for (int ks = 0; ks < 2; ++ks)
        bf[j][ks] = *(const f16x8*)(lB[bi] + (wn * 32 + j * 16 + lo) * 64 +
                                    (((ks << 2) | hi) ^ sw) * 8);
    __builtin_amdgcn_s_setprio(1);
#pragma unroll
    for (int m = 0; m < MR; ++m)
#pragma unroll
      for (int j = 0; j < 2; ++j)
#pragma unroll
        for (int ks = 0; ks < 2; ++ks)
          acc[m][j] = MFMA_F16(af[m][ks], bf[j][ks], acc[m][j]);
    __builtin_amdgcn_s_setprio(0);
    __syncthreads();  // stage(bi^1) retired + everyone done reading bi
  }
#undef GSTAGE
}

// QKV projections fused over blockIdx.z (0=Q, 1=K, 2=V-transposed+pi-permuted)
__global__ __launch_bounds__(256) void gemm_qkv(
    const f16* __restrict__ A, const f16* __restrict__ Wq,
    const f16* __restrict__ Wk, const f16* __restrict__ Wv,
    f16* __restrict__ Qo, f16* __restrict__ Ko, f16* __restrict__ VTo) {
  __shared__ __align__(16) f16 lA[2][64 * 64];
  __shared__ __align__(16) f16 lB[2][128 * 64];
  const int z = blockIdx.z;
  const f16* B = (z == 0) ? Wq : (z == 1) ? Wk : Wv;
  const int brow = blockIdx.x * 64, bcol = blockIdx.y * 128;
  f32x4 acc[4][2];
#pragma unroll
  for (int m = 0; m < 4; ++m)
#pragma unroll
    for (int j = 0; j < 2; ++j) acc[m][j] = f32x4{0.f, 0.f, 0.f, 0.f};
  gemm_mainloop<4>(A, B, brow, bcol, lA, lB, acc);
  const int lane = threadIdx.x & 63, wn = threadIdx.x >> 6;
  const int lo = lane & 15, hi = lane >> 4;
  if (z < 2) {
    f16* C = z ? Ko : Qo;
#pragma unroll
    for (int m = 0; m < 4; ++m)
#pragma unroll
      for (int j = 0; j < 2; ++j) {
        int col = bcol + wn * 32 + j * 16 + lo;
        int row0 = brow + m * 16 + hi * 4;
#pragma unroll
        for (int r = 0; r < 4; ++r)
          C[(size_t)(row0 + r) * 1024 + col] = (f16)acc[m][j][r];
      }
  } else {
    // V transposed: VT[n][s'], pi-permuted within each 64-kv block so a PV
    // fragment is one contiguous b128 in LDS.
#pragma unroll
    for (int m = 0; m < 4; ++m)
#pragma unroll
      for (int j = 0; j < 2; ++j) {
        int col = bcol + wn * 32 + j * 16 + lo;   // n
        int g = m * 4 + hi;
        int w = g & 7;
        int gp = (g & 8) | ((w < 4) ? (2 * w) : (2 * (w - 4) + 1));
        int sp = brow + gp * 4;                   // permuted s
        f16x4 v4;
#pragma unroll
        for (int r = 0; r < 4; ++r) v4[r] = (f16)acc[m][j][r];
        *(f16x4*)(VTo + (size_t)col * 2048 + sp) = v4;
      }
  }
}

// output projection: AO[2048,1024] * Wo[1024,1024]^T -> fp32 d_out
__global__ __launch_bounds__(256) void gemm_out(const f16* __restrict__ A,
                                                const f16* __restrict__ W,
                                                float* __restrict__ C) {
  __shared__ __align__(16) f16 lA[2][32 * 64];
  __shared__ __align__(16) f16 lB[2][128 * 64];
  const int brow = blockIdx.x * 32, bcol = blockIdx.y * 128;
  f32x4 acc[2][2];
#pragma unroll
  for (int m = 0; m < 2; ++m)
#pragma unroll
    for (int j = 0; j < 2; ++j) acc[m][j] = f32x4{0.f, 0.f, 0.f, 0.f};
  gemm_mainloop<2>(A, W, brow, bcol, lA, lB, acc);
  const int lane = threadIdx.x & 63, wn = threadIdx.x >> 6;
  const int lo = lane & 15, hi = lane >> 4;
#pragma unroll
  for (int m = 0; m < 2; ++m)
#pragma unroll
    for (int j = 0; j < 2; ++j) {
      int col = bcol + wn * 32 + j * 16 + lo;
      int row0 = brow + m * 16 + hi * 4;
#pragma unroll
      for (int r = 0; r < 4; ++r)
        C[(size_t)(row0 + r) * 1024 + col] = acc[m][j][r];
    }
}

// ---------------------------------------------------------------------------
// Flash attention v13 (r15, best known): 16q/wave 2-deep pipeline +
// shfl-free softmax (lane-local l, ballot-gated max), exp2 domain,
// bias-in-C-init with far-tile scalars, pi-permuted single-b128 V,
// cvt_pkrtz P pack, setprio, defer-max.
// ---------------------------------------------------------------------------
__global__ __launch_bounds__(256, 2) void attn_kernel(
    const f16* __restrict__ Q, const f16* __restrict__ K,
    const f16* __restrict__ VT, const float* __restrict__ btab,
    f16* __restrict__ AO) {
  __shared__ __align__(16) f16 lK[2][4096];
  __shared__ __align__(16) f16 lV[2][4096];

  const int h = blockIdx.y;
  const int q0 = blockIdx.x * 64;
  const int tid = threadIdx.x;
  const int wave = tid >> 6, lane = tid & 63;
  const int lo = lane & 15, hi = lane >> 4;
  const int sw = lo & 7;
  const int qlo = q0 + wave * 16;
  const int myq = qlo + lo;

  const f16* Kh = K + h * 64;
  const f16* VTh = VT + (size_t)h * 64 * 2048;
  const float* bt = btab + h * 4096 + 2047 - myq;

  // Q fragments (B-operand, cols = q): registers for whole kernel
  f16x8 qf[2];
#pragma unroll
  for (int kk = 0; kk < 2; ++kk)
    qf[kk] = *(const f16x8*)(Q + (size_t)myq * 1024 + h * 64 + kk * 32 + hi * 8);

  // far-tile scalar biases (saturated buckets), log2e-scaled
  const float bp = btab[h * 4096 + 4094];  // rel >= +91 (bucket 31)
  const float bn = btab[h * 4096 + 0];     // rel <= -91 (bucket 15)

  // staging chunk indices (2 chunks each for K and V per thread)
  const int sc0 = wave * 64 + lane;
  const int sc1 = 256 + sc0;
  const int r0 = sc0 >> 3, e0 = (sc0 & 7) ^ (r0 & 7);
  const int r1 = sc1 >> 3, e1 = (sc1 & 7) ^ (r1 & 7);

#define STAGE(bufi, kv)                                                        \
  do {                                                                         \
    ld_lds16(Kh + (size_t)((kv) + r0) * 1024 + e0 * 8, &lK[bufi][sc0 * 8]);    \
    ld_lds16(Kh + (size_t)((kv) + r1) * 1024 + e1 * 8, &lK[bufi][sc1 * 8]);    \
    ld_lds16(VTh + (size_t)r0 * 2048 + (kv) + e0 * 8, &lV[bufi][sc0 * 8]);     \
    ld_lds16(VTh + (size_t)r1 * 2048 + (kv) + e1 * 8, &lV[bufi][sc1 * 8]);     \
  } while (0)

#define BIAS_LOAD(t_, ST)                                                      \
  {                                                                            \
    const int kb_ = (t_) * 64;                                                 \
    const int rmin_ = kb_ - (qlo + 15);                                        \
    const int rmax_ = kb_ + 63 - qlo;                                          \
    if (rmin_ >= 91 || rmax_ <= -91) {                                         \
      const float bf_ = (rmin_ >= 91) ? bp : bn;                               \
      _Pragma("unroll") for (int i_ = 0; i_ < 16; ++i_) bias##ST[i_] = bf_;    \
    } else {                                                                   \
      _Pragma("unroll") for (int i_ = 0; i_ < 16; ++i_)                        \
        bias##ST[i_] = bt[kb_ + (i_ >> 2) * 16 + hi * 4 + (i_ & 3)];           \
    }                                                                          \
  }

  float m_run = -1e30f, l_run = 0.f;  // l_run is LANE-LOCAL partial
  f32x4 oacc[4];
#pragma unroll
  for (int d = 0; d < 4; ++d) oacc[d] = f32x4{0.f, 0.f, 0.f, 0.f};

  // two-tile pipeline state
  f16x8 vfA[4][2], vfB[4][2];
  f32x4 saccA[4], saccB[4];
  float biasA[16], biasB[16];

// ds-reads (K frags + V->regs as single b128s), stage next, bias(t+1)->NXT,
// QK^T into CUR with C initialized to bias##CUR
#define TILE_FRONT(t_, CUR, NXT)                                               \
  {                                                                            \
    const int b_ = (t_) & 1;                                                   \
    const f16* lKb_ = lK[b_];                                                  \
    const f16* lVb_ = lV[b_];                                                  \
    f16x8 kf_[4][2];                                                           \
    _Pragma("unroll") for (int m_ = 0; m_ < 4; ++m_)                           \
      _Pragma("unroll") for (int kk_ = 0; kk_ < 2; ++kk_)                      \
        kf_[m_][kk_] = *(const f16x8*)&lKb_[(m_ * 16 + lo) * 64 +              \
                                            (((kk_ << 2) | hi) ^ sw) * 8];     \
    _Pragma("unroll") for (int d_ = 0; d_ < 4; ++d_)                           \
      _Pragma("unroll") for (int kk_ = 0; kk_ < 2; ++kk_)                      \
        vf##CUR[d_][kk_] = *(const f16x8*)&lVb_[(d_ * 16 + lo) * 64 +          \
                                                ((kk_ * 4 + hi) ^ sw) * 8];    \
    if ((t_) < 31) STAGE(1 - b_, (t_) * 64 + 64);                              \
    if ((t_) < 31) BIAS_LOAD((t_) + 1, NXT);                                   \
    __builtin_amdgcn_s_setprio(1);                                             \
    _Pragma("unroll") for (int m_ = 0; m_ < 4; ++m_) {                         \
      sacc##CUR[m_] = f32x4{bias##CUR[m_ * 4 + 0], bias##CUR[m_ * 4 + 1],      \
                            bias##CUR[m_ * 4 + 2], bias##CUR[m_ * 4 + 3]};     \
      _Pragma("unroll") for (int kk_ = 0; kk_ < 2; ++kk_)                      \
        sacc##CUR[m_] = MFMA_F16(kf_[m_][kk_], qf[kk_], sacc##CUR[m_]);        \
    }                                                                          \
    __builtin_amdgcn_s_setprio(0);                                             \
  }

// softmax (exp2 domain, shfl-free common path) + PV for tile in PRV state
#define SOFTMAX_PV(PRV)                                                        \
  {                                                                            \
    float p_[16];                                                              \
    _Pragma("unroll") for (int i_ = 0; i_ < 16; ++i_)                          \
      p_[i_] = sacc##PRV[i_ >> 2][i_ & 3];                                     \
    float x8_[8];                                                              \
    _Pragma("unroll") for (int i_ = 0; i_ < 8; ++i_)                           \
      x8_[i_] = fmaxf(p_[i_], p_[i_ + 8]);                                     \
    float x4_[4];                                                              \
    _Pragma("unroll") for (int i_ = 0; i_ < 4; ++i_)                           \
      x4_[i_] = fmaxf(x8_[i_], x8_[i_ + 4]);                                   \
    float mxl_ = fmaxf(fmaxf(x4_[0], x4_[1]), fmaxf(x4_[2], x4_[3]));          \
    if (!__all(mxl_ <= m_run + 11.5416f)) {  /* rare: real max update */       \
      float mx_ = fmaxf(mxl_, __shfl_xor(mxl_, 16, 64));                       \
      mx_ = fmaxf(mx_, __shfl_xor(mx_, 32, 64));                               \
      float mn_ = fmaxf(m_run, mx_);                                           \
      float sc_ = EXP2(m_run - mn_);                                           \
      l_run *= sc_;                                                            \
      _Pragma("unroll") for (int d_ = 0; d_ < 4; ++d_) oacc[d_] *= sc_;        \
      m_run = mn_;                                                             \
    }                                                                          \
    _Pragma("unroll") for (int i_ = 0; i_ < 16; ++i_)                          \
      p_[i_] = EXP2(p_[i_] - m_run);                                           \
    float s8_[8];                                                              \
    _Pragma("unroll") for (int i_ = 0; i_ < 8; ++i_)                           \
      s8_[i_] = p_[i_] + p_[i_ + 8];                                           \
    float s4_[4];                                                              \
    _Pragma("unroll") for (int i_ = 0; i_ < 4; ++i_)                           \
      s4_[i_] = s8_[i_] + s8_[i_ + 4];                                         \
    l_run += (s4_[0] + s4_[1]) + (s4_[2] + s4_[3]); /* lane-local */           \
    f16x8 pf_[2];                                                              \
    _Pragma("unroll") for (int kk_ = 0; kk_ < 2; ++kk_) {                      \
      union {                                                                  \
        h16x2 h2[4];                                                           \
        f16x8 v8;                                                              \
      } u_;                                                                    \
      _Pragma("unroll") for (int j_ = 0; j_ < 4; ++j_)                         \
        u_.h2[j_] = __builtin_amdgcn_cvt_pkrtz(p_[kk_ * 8 + 2 * j_],           \
                                               p_[kk_ * 8 + 2 * j_ + 1]);      \
      pf_[kk_] = u_.v8;                                                        \
    }                                                                          \
    __builtin_amdgcn_s_setprio(1);                                             \
    _Pragma("unroll") for (int d_ = 0; d_ < 4; ++d_)                           \
      _Pragma("unroll") for (int kk_ = 0; kk_ < 2; ++kk_)                      \
        oacc[d_] = MFMA_F16(vf##PRV[d_][kk_], pf_[kk_], oacc[d_]);             \
    __builtin_amdgcn_s_setprio(0);                                             \
  }

  BIAS_LOAD(0, A);
  STAGE(0, 0);
  __syncthreads();

  TILE_FRONT(0, A, B);
  __syncthreads();

  for (int k2 = 0; k2 < 15; ++k2) {
    const int t1 = 2 * k2 + 1;
    TILE_FRONT(t1, B, A);
    SOFTMAX_PV(A);
    __syncthreads();
    TILE_FRONT(t1 + 1, A, B);
    SOFTMAX_PV(B);
    __syncthreads();
  }
  TILE_FRONT(31, B, A);
  SOFTMAX_PV(A);
  SOFTMAX_PV(B);

#undef TILE_FRONT
#undef SOFTMAX_PV
#undef BIAS_LOAD
#undef STAGE

  // ---- epilogue: cross-lane l reduce (deferred), then O/l -> AO ----
  l_run += __shfl_xor(l_run, 16, 64);
  l_run += __shfl_xor(l_run, 32, 64);
  float inv = 1.f / l_run;
#pragma unroll
  for (int d = 0; d < 4; ++d) {
    f16x4 ov;
#pragma unroll
    for (int r = 0; r < 4; ++r) ov[r] = (f16)(oacc[d][r] * inv);
    *(f16x4*)(AO + (size_t)myq * 1024 + h * 64 + d * 16 + hi * 4) = ov;
  }
}

// ---------------------------------------------------------------------------
extern "C" void kernel_launch(void* const* d_in, const int* in_sizes, int n_in,
                              void* d_out, int out_size, void* d_ws, size_t ws_size,
                              hipStream_t stream) {
  const float* hs = (const float*)d_in[0];
  const float* wq = (const float*)d_in[1];
  const float* wk = (const float*)d_in[2];
  const float* wv = (const float*)d_in[3];
  const float* wo = (const float*)d_in[4];
  const float* rb = (const float*)d_in[5];

  char* w = (char*)d_ws;
  f16* hb  = (f16*)w; w += (size_t)2048 * 1024 * 2;
  f16* wqb = (f16*)w; w += (size_t)1024 * 1024 * 2;
  f16* wkb = (f16*)w; w += (size_t)1024 * 1024 * 2;
  f16* wvb = (f16*)w; w += (size_t)1024 * 1024 * 2;
  f16* wob = (f16*)w; w += (size_t)1024 * 1024 * 2;
  f16* Qb  = (f16*)w; w += (size_t)2048 * 1024 * 2;
  f16* Kb  = (f16*)w; w += (size_t)2048 * 1024 * 2;
  f16* VTb = (f16*)w; w += (size_t)2048 * 1024 * 2;
  f16* AOb = (f16*)w; w += (size_t)2048 * 1024 * 2;
  float* btab = (float*)w; w += (size_t)16 * 4096 * 4;

  cast_and_bias<<<6400, 256, 0, stream>>>(hs, wq, wk, wv, wo, rb,
                                          hb, wqb, wkb, wvb, wob, btab);
  gemm_qkv<<<dim3(32, 8, 3), 256, 0, stream>>>(hb, wqb, wkb, wvb, Qb, Kb, VTb);
  attn_kernel<<<dim3(32, 16), 256, 0, stream>>>(Qb, Kb, VTb, btab, AOb);
  gemm_out<<<dim3(64, 8), 256, 0, stream>>>(AOb, wob, (float*)d_out);
}

// Round 18
// 78.344 us; speedup vs baseline: 1.3212x; 1.0023x over previous
//
#include <hip/hip_runtime.h>
#include <hip/hip_bf16.h>

typedef _Float16 f16;
typedef f16 f16x8 __attribute__((ext_vector_type(8)));
typedef f16 f16x4 __attribute__((ext_vector_type(4)));
typedef __fp16 h16x2 __attribute__((ext_vector_type(2)));
typedef float f32x4 __attribute__((ext_vector_type(4)));

#define MFMA_F16(a, b, c) __builtin_amdgcn_mfma_f32_16x16x32_f16((a), (b), (c), 0, 0, 0)
#define LOG2E 1.44269504f
#define EXP2(x) __builtin_amdgcn_exp2f(x)

// ---------------------------------------------------------------------------
// async global->LDS 16B copy
// ---------------------------------------------------------------------------
__device__ __forceinline__ void ld_lds16(const void* g, void* l) {
  __builtin_amdgcn_global_load_lds((const __attribute__((address_space(1))) void*)g,
                                   (__attribute__((address_space(3))) void*)l, 16, 0, 0);
}

// ---------------------------------------------------------------------------
// fused: cast fp32 -> fp16 (wq scaled by log2e) + bias table build
// blocks [0,6144): cast;  blocks [6144,6400): bias
// ---------------------------------------------------------------------------
__global__ __launch_bounds__(256) void cast_and_bias(
    const float* __restrict__ hs, const float* __restrict__ wq,
    const float* __restrict__ wk, const float* __restrict__ wv,
    const float* __restrict__ wo, const float* __restrict__ rb,
    f16* __restrict__ hb, f16* __restrict__ wqb, f16* __restrict__ wkb,
    f16* __restrict__ wvb, f16* __restrict__ wob, float* __restrict__ btab) {
  if (blockIdx.x < 6144) {
    int idx = blockIdx.x * 256 + threadIdx.x;  // 1,572,864 float4 chunks
    const float* src;
    f16* dst;
    int j;
    float scale = 1.0f;
    if (idx < 524288) {  // hidden: 2M floats / 4
      src = hs; dst = hb; j = idx;
    } else {
      int t = idx - 524288;
      int w = t >> 18;      // 262144 float4 per weight
      j = t & 262143;
      src = (w == 0) ? wq : (w == 1) ? wk : (w == 2) ? wv : wo;
      dst = (w == 0) ? wqb : (w == 1) ? wkb : (w == 2) ? wvb : wob;
      if (w == 0) scale = LOG2E;
    }
    float4 v = ((const float4*)src)[j];
    f16x4 o;
    o[0] = (f16)(v.x * scale); o[1] = (f16)(v.y * scale);
    o[2] = (f16)(v.z * scale); o[3] = (f16)(v.w * scale);
    ((f16x4*)dst)[j] = o;
  } else {
    int idx = (blockIdx.x - 6144) * 256 + threadIdx.x;  // 65536 = 16h * 4096
    int h = idx >> 12;
    int t = idx & 4095;
    int rel = t - 2047;
    int bucket = (rel > 0) ? 16 : 0;
    int a = (rel < 0) ? -rel : rel;
    int lg;
    if (a < 8) {
      lg = a;
    } else {
      int cnt = (a >= 12) + (a >= 16) + (a >= 23) + (a >= 32) + (a >= 46) +
                (a >= 64) + (a >= 91);
      lg = 8 + cnt;  // max 15
    }
    bucket += lg;
    btab[idx] = rb[bucket * 16 + h] * LOG2E;  // rel_bias[32][16]
  }
}

// ---------------------------------------------------------------------------
// GEMM mainloop, templated on MR: MR=4 -> 64x128 tile, MR=2 -> 32x128 tile.
// Double-buffered: stage(k+64) before compute(k), one barrier/iter.
// ---------------------------------------------------------------------------
template <int MR>
__device__ __forceinline__ void gemm_mainloop(const f16* __restrict__ A,
                                              const f16* __restrict__ B,
                                              int brow, int bcol,
                                              f16 (*lA)[MR * 16 * 64],
                                              f16 (*lB)[128 * 64],
                                              f32x4 acc[MR][2]) {
  const int tid = threadIdx.x;
  const int lane = tid & 63;
  const int wn = tid >> 6;
  const int lo = lane & 15;
  const int hi = lane >> 4;
  const int sw = lo & 7;
  const int sr = tid >> 3;                       // 0..31
  const int se = (((tid & 7) ^ (sr & 7)) << 3);  // swizzled col elem offset
  const f16* gA = A + (size_t)(brow + sr) * 1024 + se;
  const f16* gB = B + (size_t)(bcol + sr) * 1024 + se;

#define GSTAGE(bi, k0_)                                                        \
  do {                                                                         \
    ld_lds16(gA + (k0_), lA[bi] + tid * 8);                                    \
    if constexpr (MR == 4)                                                     \
      ld_lds16(gA + (k0_) + 32 * 1024, lA[bi] + tid * 8 + 2048);               \
    ld_lds16(gB + (k0_),             lB[bi] + tid * 8);                        \
    ld_lds16(gB + (k0_) + 32 * 1024, lB[bi] + tid * 8 + 2048);                 \
    ld_lds16(gB + (k0_) + 64 * 1024, lB[bi] + tid * 8 + 4096);                 \
    ld_lds16(gB + (k0_) + 96 * 1024, lB[bi] + tid * 8 + 6144);                 \
  } while (0)

  GSTAGE(0, 0);
  __syncthreads();
  for (int k0 = 0; k0 < 1024; k0 += 64) {
    const int bi = (k0 >> 6) & 1;
    if (k0 < 960) GSTAGE(bi ^ 1, k0 + 64);
    f16x8 af[MR][2], bf[2][2];
#pragma unroll
    for (int m = 0; m < MR; ++m)
#pragma unroll
      for (int ks = 0; ks < 2; ++ks)
        af[m][ks] = *(const f16x8*)(lA[bi] + (m * 16 + lo) * 64 +
                                    (((ks << 2) | hi) ^ sw) * 8);
#pragma unroll
    for (int j = 0; j < 2; ++j)
#pragma unroll
      for (int ks = 0; ks < 2; ++ks)
        bf[j][ks] = *(const f16x8*)(lB[bi] + (wn * 32 + j * 16 + lo) * 64 +
                                    (((ks << 2) | hi) ^ sw) * 8);
    __builtin_amdgcn_s_setprio(1);
#pragma unroll
    for (int m = 0; m < MR; ++m)
#pragma unroll
      for (int j = 0; j < 2; ++j)
#pragma unroll
        for (int ks = 0; ks < 2; ++ks)
          acc[m][j] = MFMA_F16(af[m][ks], bf[j][ks], acc[m][j]);
    __builtin_amdgcn_s_setprio(0);
    __syncthreads();  // stage(bi^1) retired + everyone done reading bi
  }
#undef GSTAGE
}

// QKV projections fused over blockIdx.z (0=Q, 1=K, 2=V-transposed+pi-permuted)
__global__ __launch_bounds__(256) void gemm_qkv(
    const f16* __restrict__ A, const f16* __restrict__ Wq,
    const f16* __restrict__ Wk, const f16* __restrict__ Wv,
    f16* __restrict__ Qo, f16* __restrict__ Ko, f16* __restrict__ VTo) {
  __shared__ __align__(16) f16 lA[2][64 * 64];
  __shared__ __align__(16) f16 lB[2][128 * 64];
  const int z = blockIdx.z;
  const f16* B = (z == 0) ? Wq : (z == 1) ? Wk : Wv;
  const int brow = blockIdx.x * 64, bcol = blockIdx.y * 128;
  f32x4 acc[4][2];
#pragma unroll
  for (int m = 0; m < 4; ++m)
#pragma unroll
    for (int j = 0; j < 2; ++j) acc[m][j] = f32x4{0.f, 0.f, 0.f, 0.f};
  gemm_mainloop<4>(A, B, brow, bcol, lA, lB, acc);
  const int lane = threadIdx.x & 63, wn = threadIdx.x >> 6;
  const int lo = lane & 15, hi = lane >> 4;
  if (z < 2) {
    f16* C = z ? Ko : Qo;
#pragma unroll
    for (int m = 0; m < 4; ++m)
#pragma unroll
      for (int j = 0; j < 2; ++j) {
        int col = bcol + wn * 32 + j * 16 + lo;
        int row0 = brow + m * 16 + hi * 4;
#pragma unroll
        for (int r = 0; r < 4; ++r)
          C[(size_t)(row0 + r) * 1024 + col] = (f16)acc[m][j][r];
      }
  } else {
    // V transposed: VT[n][s'], pi-permuted within each 64-kv block so a PV
    // fragment is one contiguous b128 in LDS.
#pragma unroll
    for (int m = 0; m < 4; ++m)
#pragma unroll
      for (int j = 0; j < 2; ++j) {
        int col = bcol + wn * 32 + j * 16 + lo;   // n
        int g = m * 4 + hi;
        int w = g & 7;
        int gp = (g & 8) | ((w < 4) ? (2 * w) : (2 * (w - 4) + 1));
        int sp = brow + gp * 4;                   // permuted s
        f16x4 v4;
#pragma unroll
        for (int r = 0; r < 4; ++r) v4[r] = (f16)acc[m][j][r];
        *(f16x4*)(VTo + (size_t)col * 2048 + sp) = v4;
      }
  }
}

// output projection: AO[2048,1024] * Wo[1024,1024]^T -> fp32 d_out
__global__ __launch_bounds__(256) void gemm_out(const f16* __restrict__ A,
                                                const f16* __restrict__ W,
                                                float* __restrict__ C) {
  __shared__ __align__(16) f16 lA[2][32 * 64];
  __shared__ __align__(16) f16 lB[2][128 * 64];
  const int brow = blockIdx.x * 32, bcol = blockIdx.y * 128;
  f32x4 acc[2][2];
#pragma unroll
  for (int m = 0; m < 2; ++m)
#pragma unroll
    for (int j = 0; j < 2; ++j) acc[m][j] = f32x4{0.f, 0.f, 0.f, 0.f};
  gemm_mainloop<2>(A, W, brow, bcol, lA, lB, acc);
  const int lane = threadIdx.x & 63, wn = threadIdx.x >> 6;
  const int lo = lane & 15, hi = lane >> 4;
#pragma unroll
  for (int m = 0; m < 2; ++m)
#pragma unroll
    for (int j = 0; j < 2; ++j) {
      int col = bcol + wn * 32 + j * 16 + lo;
      int row0 = brow + m * 16 + hi * 4;
#pragma unroll
      for (int r = 0; r < 4; ++r)
        C[(size_t)(row0 + r) * 1024 + col] = acc[m][j][r];
    }
}

// ---------------------------------------------------------------------------
// Flash attention v13 (r15, best known): 16q/wave 2-deep pipeline +
// shfl-free softmax (lane-local l, ballot-gated max), exp2 domain,
// bias-in-C-init with far-tile scalars, pi-permuted single-b128 V,
// cvt_pkrtz P pack, setprio, defer-max.
// ---------------------------------------------------------------------------
__global__ __launch_bounds__(256, 2) void attn_kernel(
    const f16* __restrict__ Q, const f16* __restrict__ K,
    const f16* __restrict__ VT, const float* __restrict__ btab,
    f16* __restrict__ AO) {
  __shared__ __align__(16) f16 lK[2][4096];
  __shared__ __align__(16) f16 lV[2][4096];

  const int h = blockIdx.y;
  const int q0 = blockIdx.x * 64;
  const int tid = threadIdx.x;
  const int wave = tid >> 6, lane = tid & 63;
  const int lo = lane & 15, hi = lane >> 4;
  const int sw = lo & 7;
  const int qlo = q0 + wave * 16;
  const int myq = qlo + lo;

  const f16* Kh = K + h * 64;
  const f16* VTh = VT + (size_t)h * 64 * 2048;
  const float* bt = btab + h * 4096 + 2047 - myq;

  // Q fragments (B-operand, cols = q): registers for whole kernel
  f16x8 qf[2];
#pragma unroll
  for (int kk = 0; kk < 2; ++kk)
    qf[kk] = *(const f16x8*)(Q + (size_t)myq * 1024 + h * 64 + kk * 32 + hi * 8);

  // far-tile scalar biases (saturated buckets), log2e-scaled
  const float bp = btab[h * 4096 + 4094];  // rel >= +91 (bucket 31)
  const float bn = btab[h * 4096 + 0];     // rel <= -91 (bucket 15)

  // staging chunk indices (2 chunks each for K and V per thread)
  const int sc0 = wave * 64 + lane;
  const int sc1 = 256 + sc0;
  const int r0 = sc0 >> 3, e0 = (sc0 & 7) ^ (r0 & 7);
  const int r1 = sc1 >> 3, e1 = (sc1 & 7) ^ (r1 & 7);

#define STAGE(bufi, kv)                                                        \
  do {                                                                         \
    ld_lds16(Kh + (size_t)((kv) + r0) * 1024 + e0 * 8, &lK[bufi][sc0 * 8]);    \
    ld_lds16(Kh + (size_t)((kv) + r1) * 1024 + e1 * 8, &lK[bufi][sc1 * 8]);    \
    ld_lds16(VTh + (size_t)r0 * 2048 + (kv) + e0 * 8, &lV[bufi][sc0 * 8]);     \
    ld_lds16(VTh + (size_t)r1 * 2048 + (kv) + e1 * 8, &lV[bufi][sc1 * 8]);     \
  } while (0)

#define BIAS_LOAD(t_, ST)                                                      \
  {                                                                            \
    const int kb_ = (t_) * 64;                                                 \
    const int rmin_ = kb_ - (qlo + 15);                                        \
    const int rmax_ = kb_ + 63 - qlo;                                          \
    if (rmin_ >= 91 || rmax_ <= -91) {                                         \
      const float bf_ = (rmin_ >= 91) ? bp : bn;                               \
      _Pragma("unroll") for (int i_ = 0; i_ < 16; ++i_) bias##ST[i_] = bf_;    \
    } else {                                                                   \
      _Pragma("unroll") for (int i_ = 0; i_ < 16; ++i_)                        \
        bias##ST[i_] = bt[kb_ + (i_ >> 2) * 16 + hi * 4 + (i_ & 3)];           \
    }                                                                          \
  }

  float m_run = -1e30f, l_run = 0.f;  // l_run is LANE-LOCAL partial
  f32x4 oacc[4];
#pragma unroll
  for (int d = 0; d < 4; ++d) oacc[d] = f32x4{0.f, 0.f, 0.f, 0.f};

  // two-tile pipeline state
  f16x8 vfA[4][2], vfB[4][2];
  f32x4 saccA[4], saccB[4];
  float biasA[16], biasB[16];

// ds-reads (K frags + V->regs as single b128s), stage next, bias(t+1)->NXT,
// QK^T into CUR with C initialized to bias##CUR
#define TILE_FRONT(t_, CUR, NXT)                                               \
  {                                                                            \
    const int b_ = (t_) & 1;                                                   \
    const f16* lKb_ = lK[b_];                                                  \
    const f16* lVb_ = lV[b_];                                                  \
    f16x8 kf_[4][2];                                                           \
    _Pragma("unroll") for (int m_ = 0; m_ < 4; ++m_)                           \
      _Pragma("unroll") for (int kk_ = 0; kk_ < 2; ++kk_)                      \
        kf_[m_][kk_] = *(const f16x8*)&lKb_[(m_ * 16 + lo) * 64 +              \
                                            (((kk_ << 2) | hi) ^ sw) * 8];     \
    _Pragma("unroll") for (int d_ = 0; d_ < 4; ++d_)                           \
      _Pragma("unroll") for (int kk_ = 0; kk_ < 2; ++kk_)                      \
        vf##CUR[d_][kk_] = *(const f16x8*)&lVb_[(d_ * 16 + lo) * 64 +          \
                                                ((kk_ * 4 + hi) ^ sw) * 8];    \
    if ((t_) < 31) STAGE(1 - b_, (t_) * 64 + 64);                              \
    if ((t_) < 31) BIAS_LOAD((t_) + 1, NXT);                                   \
    __builtin_amdgcn_s_setprio(1);                                             \
    _Pragma("unroll") for (int m_ = 0; m_ < 4; ++m_) {                         \
      sacc##CUR[m_] = f32x4{bias##CUR[m_ * 4 + 0], bias##CUR[m_ * 4 + 1],      \
                            bias##CUR[m_ * 4 + 2], bias##CUR[m_ * 4 + 3]};     \
      _Pragma("unroll") for (int kk_ = 0; kk_ < 2; ++kk_)                      \
        sacc##CUR[m_] = MFMA_F16(kf_[m_][kk_], qf[kk_], sacc##CUR[m_]);        \
    }                                                                          \
    __builtin_amdgcn_s_setprio(0);                                             \
  }

// softmax (exp2 domain, shfl-free common path) + PV for tile in PRV state
#define SOFTMAX_PV(PRV)                                                        \
  {                                                                            \
    float p_[16];                                                              \
    _Pragma("unroll") for (int i_ = 0; i_ < 16; ++i_)                          \
      p_[i_] = sacc##PRV[i_ >> 2][i_ & 3];                                     \
    float x8_[8];                                                              \
    _Pragma("unroll") for (int i_ = 0; i_ < 8; ++i_)                           \
      x8_[i_] = fmaxf(p_[i_], p_[i_ + 8]);                                     \
    float x4_[4];                                                              \
    _Pragma("unroll") for (int i_ = 0; i_ < 4; ++i_)                           \
      x4_[i_] = fmaxf(x8_[i_], x8_[i_ + 4]);                                   \
    float mxl_ = fmaxf(fmaxf(x4_[0], x4_[1]), fmaxf(x4_[2], x4_[3]));          \
    if (!__all(mxl_ <= m_run + 11.5416f)) {  /* rare: real max update */       \
      float mx_ = fmaxf(mxl_, __shfl_xor(mxl_, 16, 64));                       \
      mx_ = fmaxf(mx_, __shfl_xor(mx_, 32, 64));                               \
      float mn_ = fmaxf(m_run, mx_);                                           \
      float sc_ = EXP2(m_run - mn_);                                           \
      l_run *= sc_;                                                            \
      _Pragma("unroll") for (int d_ = 0; d_ < 4; ++d_) oacc[d_] *= sc_;        \
      m_run = mn_;                                                             \
    }                                                                          \
    _Pragma("unroll") for (int i_ = 0; i_ < 16; ++i_)                          \
      p_[i_] = EXP2(p_[i_] - m_run);                                           \
    float s8_[8];                                                              \
    _Pragma("unroll") for (int i_ = 0; i_ < 8; ++i_)                           \
      s8_[i_] = p_[i_] + p_[i_ + 8];                                           \
    float s4_[4];                                                              \
    _Pragma("unroll") for (int i_ = 0; i_ < 4; ++i_)                           \
      s4_[i_] = s8_[i_] + s8_[i_ + 4];                                         \
    l_run += (s4_[0] + s4_[1]) + (s4_[2] + s4_[3]); /* lane-local */           \
    f16x8 pf_[2];                                                              \
    _Pragma("unroll") for (int kk_ = 0; kk_ < 2; ++kk_) {                      \
      union {                                                                  \
        h16x2 h2[4];                                                           \
        f16x8 v8;                                                              \
      } u_;                                                                    \
      _Pragma("unroll") for (int j_ = 0; j_ < 4; ++j_)                         \
        u_.h2[j_] = __builtin_amdgcn_cvt_pkrtz(p_[kk_ * 8 + 2 * j_],           \
                                               p_[kk_ * 8 + 2 * j_ + 1]);      \
      pf_[kk_] = u_.v8;                                                        \
    }                                                                          \
    __builtin_amdgcn_s_setprio(1);                                             \
    _Pragma("unroll") for (int d_ = 0; d_ < 4; ++d_)                           \
      _Pragma("unroll") for (int kk_ = 0; kk_ < 2; ++kk_)                      \
        oacc[d_] = MFMA_F16(vf##PRV[d_][kk_], pf_[kk_], oacc[d_]);             \
    __builtin_amdgcn_s_setprio(0);                                             \
  }

  BIAS_LOAD(0, A);
  STAGE(0, 0);
  __syncthreads();

  TILE_FRONT(0, A, B);
  __syncthreads();

  for (int k2 = 0; k2 < 15; ++k2) {
    const int t1 = 2 * k2 + 1;
    TILE_FRONT(t1, B, A);
    SOFTMAX_PV(A);
    __syncthreads();
    TILE_FRONT(t1 + 1, A, B);
    SOFTMAX_PV(B);
    __syncthreads();
  }
  TILE_FRONT(31, B, A);
  SOFTMAX_PV(A);
  SOFTMAX_PV(B);

#undef TILE_FRONT
#undef SOFTMAX_PV
#undef BIAS_LOAD
#undef STAGE

  // ---- epilogue: cross-lane l reduce (deferred), then O/l -> AO ----
  l_run += __shfl_xor(l_run, 16, 64);
  l_run += __shfl_xor(l_run, 32, 64);
  float inv = 1.f / l_run;
#pragma unroll
  for (int d = 0; d < 4; ++d) {
    f16x4 ov;
#pragma unroll
    for (int r = 0; r < 4; ++r) ov[r] = (f16)(oacc[d][r] * inv);
    *(f16x4*)(AO + (size_t)myq * 1024 + h * 64 + d * 16 + hi * 4) = ov;
  }
}

// ---------------------------------------------------------------------------
extern "C" void kernel_launch(void* const* d_in, const int* in_sizes, int n_in,
                              void* d_out, int out_size, void* d_ws, size_t ws_size,
                              hipStream_t stream) {
  const float* hs = (const float*)d_in[0];
  const float* wq = (const float*)d_in[1];
  const float* wk = (const float*)d_in[2];
  const float* wv = (const float*)d_in[3];
  const float* wo = (const float*)d_in[4];
  const float* rb = (const float*)d_in[5];

  char* w = (char*)d_ws;
  f16* hb  = (f16*)w; w += (size_t)2048 * 1024 * 2;
  f16* wqb = (f16*)w; w += (size_t)1024 * 1024 * 2;
  f16* wkb = (f16*)w; w += (size_t)1024 * 1024 * 2;
  f16* wvb = (f16*)w; w += (size_t)1024 * 1024 * 2;
  f16* wob = (f16*)w; w += (size_t)1024 * 1024 * 2;
  f16* Qb  = (f16*)w; w += (size_t)2048 * 1024 * 2;
  f16* Kb  = (f16*)w; w += (size_t)2048 * 1024 * 2;
  f16* VTb = (f16*)w; w += (size_t)2048 * 1024 * 2;
  f16* AOb = (f16*)w; w += (size_t)2048 * 1024 * 2;
  float* btab = (float*)w; w += (size_t)16 * 4096 * 4;

  cast_and_bias<<<6400, 256, 0, stream>>>(hs, wq, wk, wv, wo, rb,
                                          hb, wqb, wkb, wvb, wob, btab);
  gemm_qkv<<<dim3(32, 8, 3), 256, 0, stream>>>(hb, wqb, wkb, wvb, Qb, Kb, VTb);
  attn_kernel<<<dim3(32, 16), 256, 0, stream>>>(Qb, Kb, VTb, btab, AOb);
  gemm_out<<<dim3(64, 8), 256, 0, stream>>>(AOb, wob, (float*)d_out);
}